// Round 6
// baseline (12635.339 us; speedup 1.0000x reference)
//
#include <hip/hip_runtime.h>
#include <hip/hip_bf16.h>

#define T_SEQ 8192
#define E_DIM 256
#define H_DIM 512
#define G4    2048   // 4*H
#define NBD   32     // blocks per direction
#define JPB   16     // h-elements per block

// ======================================================================
// K1: pre[dir][t][0:2048] = emb[sent(dir,t)] @ W_ih[dir]^T + (b_ih+b_hh)
// ======================================================================
__global__ __launch_bounds__(256, 4)
void k_pre(const int* __restrict__ sent, const float* __restrict__ emb,
           const float* __restrict__ Wf, const float* __restrict__ Wb,
           const float* __restrict__ bif, const float* __restrict__ bhf,
           const float* __restrict__ bib, const float* __restrict__ bhb,
           float* __restrict__ pre)
{
    const int jt  = blockIdx.x;
    const int tt  = blockIdx.y;
    const int dir = blockIdx.z;
    const float* W  = dir ? Wb : Wf;
    const float* bi = dir ? bib : bif;
    const float* bh = dir ? bhb : bhf;
    float* pred = pre + (size_t)dir * T_SEQ * G4;

    __shared__ float xs[64][65];
    __shared__ float ws[64][65];
    __shared__ int   ss[64];

    const int tid = threadIdx.x;
    if (tid < 64) {
        int trow = tt * 64 + tid;
        ss[tid] = sent[dir ? (T_SEQ - 1 - trow) : trow];
    }

    const int ty = tid >> 4, tx = tid & 15;
    const int lrow  = tid >> 2;
    const int cbase = (tid & 3) * 16;

    float acc[4][4] = {{0.f}};

    for (int kk0 = 0; kk0 < E_DIM; kk0 += 64) {
        __syncthreads();
        #pragma unroll
        for (int c = 0; c < 4; ++c) {
            int col = cbase + c * 4;
            float4 xv = *reinterpret_cast<const float4*>(emb + (size_t)ss[lrow] * E_DIM + kk0 + col);
            float4 wv = *reinterpret_cast<const float4*>(W + (size_t)(jt * 64 + lrow) * E_DIM + kk0 + col);
            xs[lrow][col+0] = xv.x; xs[lrow][col+1] = xv.y; xs[lrow][col+2] = xv.z; xs[lrow][col+3] = xv.w;
            ws[lrow][col+0] = wv.x; ws[lrow][col+1] = wv.y; ws[lrow][col+2] = wv.z; ws[lrow][col+3] = wv.w;
        }
        __syncthreads();
        #pragma unroll 8
        for (int k = 0; k < 64; ++k) {
            float a0 = xs[ty*4+0][k], a1 = xs[ty*4+1][k], a2 = xs[ty*4+2][k], a3 = xs[ty*4+3][k];
            float b0 = ws[tx*4+0][k], b1 = ws[tx*4+1][k], b2 = ws[tx*4+2][k], b3 = ws[tx*4+3][k];
            acc[0][0] = fmaf(a0,b0,acc[0][0]); acc[0][1] = fmaf(a0,b1,acc[0][1]);
            acc[0][2] = fmaf(a0,b2,acc[0][2]); acc[0][3] = fmaf(a0,b3,acc[0][3]);
            acc[1][0] = fmaf(a1,b0,acc[1][0]); acc[1][1] = fmaf(a1,b1,acc[1][1]);
            acc[1][2] = fmaf(a1,b2,acc[1][2]); acc[1][3] = fmaf(a1,b3,acc[1][3]);
            acc[2][0] = fmaf(a2,b0,acc[2][0]); acc[2][1] = fmaf(a2,b1,acc[2][1]);
            acc[2][2] = fmaf(a2,b2,acc[2][2]); acc[2][3] = fmaf(a2,b3,acc[2][3]);
            acc[3][0] = fmaf(a3,b0,acc[3][0]); acc[3][1] = fmaf(a3,b1,acc[3][1]);
            acc[3][2] = fmaf(a3,b2,acc[3][2]); acc[3][3] = fmaf(a3,b3,acc[3][3]);
        }
    }

    const int colg = jt * 64 + tx * 4;
    float bs[4];
    #pragma unroll
    for (int j = 0; j < 4; ++j) bs[j] = bi[colg + j] + bh[colg + j];
    #pragma unroll
    for (int i = 0; i < 4; ++i) {
        float4 r;
        r.x = acc[i][0] + bs[0]; r.y = acc[i][1] + bs[1];
        r.z = acc[i][2] + bs[2]; r.w = acc[i][3] + bs[3];
        *reinterpret_cast<float4*>(pred + (size_t)(tt*64 + ty*4 + i) * G4 + colg) = r;
    }
}

// ---------- fast activations (no NaN for large |x|) ----------
__device__ __forceinline__ float sigmoid_f(float x) {
    return 1.f / (1.f + __expf(-x));
}
__device__ __forceinline__ float tanh_f(float x) {
    float e = __expf(2.f * fabsf(x));            // inf ok: 2/(inf+1)=0
    float r = 1.f - 2.f / (e + 1.f);
    return copysignf(r, x);
}

// pin a float4's components into VGPRs (opaque to rematerialization)
#define PIN4(v) do { \
    asm volatile("" : "+v"(v.x)); asm volatile("" : "+v"(v.y)); \
    asm volatile("" : "+v"(v.z)); asm volatile("" : "+v"(v.w)); } while (0)

#define DOT8(a4, b4, P, Q) \
    fmaf(a4.x, P.x, fmaf(a4.y, P.y, fmaf(a4.z, P.z, fmaf(a4.w, P.w, \
    fmaf(b4.x, Q.x, fmaf(b4.y, Q.y, fmaf(b4.z, Q.z, b4.w * Q.w)))))))

// ======================================================================
// K2: two LSTM scans. 64 persistent blocks (32/dir) x 512 threads.
// Block owns 16 h-outputs (64 gate-rows). Thread: 8 rows x 8 cols = 64
// weights in 16 NAMED float4s -- no local arrays anywhere (R1-R5 lesson:
// loop-indexed local arrays are demoted to scratch by SROA *before*
// unrolling; VGPR stuck at 52 and every step reloaded 256B/thread from
// scratch/L2 = the 2900cy/step wall). Explicit named-scalar butterfly.
// h exchange: step-tagged 64-bit agent-scope atomics, parity dbuf.
// ======================================================================
__global__ __launch_bounds__(512, 1)
void k_scan(const float* __restrict__ pre,
            const float* __restrict__ Whhf, const float* __restrict__ Whhb,
            const float* __restrict__ h0, const float* __restrict__ c0,
            float* __restrict__ hcat, unsigned long long* __restrict__ hbuf)
{
    const int bid  = blockIdx.x;
    const int dir  = (bid >> 2) & 1;
    const int b    = (bid >> 3) * 4 + (bid & 3);   // 0..31 within dir
    const int tid  = threadIdx.x;
    const int wv   = tid >> 6;          // 0..7
    const int lane = tid & 63;
    const int r    = lane & 7;          // this lane's home row (post-reduce)
    const int gme  = r & 3;             // gate of home row
    const int j_me = b * JPB + wv * 2 + (r >> 2);
    const int row_me = gme * H_DIM + j_me;          // for pre prefetch

    const float* Whh = dir ? Whhb : Whhf;
    const int jbase = b * JPB + wv * 2;
    // row index for sub-row r2: (r2&3)*H + jbase + (r2>>2)
    #define WROW(r2) (Whh + (size_t)(((r2) & 3) * H_DIM + jbase + ((r2) >> 2)) * H_DIM)
    float4 p0 = *reinterpret_cast<const float4*>(WROW(0) + 4 * lane);
    float4 q0 = *reinterpret_cast<const float4*>(WROW(0) + 256 + 4 * lane);
    float4 p1 = *reinterpret_cast<const float4*>(WROW(1) + 4 * lane);
    float4 q1 = *reinterpret_cast<const float4*>(WROW(1) + 256 + 4 * lane);
    float4 p2 = *reinterpret_cast<const float4*>(WROW(2) + 4 * lane);
    float4 q2 = *reinterpret_cast<const float4*>(WROW(2) + 256 + 4 * lane);
    float4 p3 = *reinterpret_cast<const float4*>(WROW(3) + 4 * lane);
    float4 q3 = *reinterpret_cast<const float4*>(WROW(3) + 256 + 4 * lane);
    float4 p4 = *reinterpret_cast<const float4*>(WROW(4) + 4 * lane);
    float4 q4 = *reinterpret_cast<const float4*>(WROW(4) + 256 + 4 * lane);
    float4 p5 = *reinterpret_cast<const float4*>(WROW(5) + 4 * lane);
    float4 q5 = *reinterpret_cast<const float4*>(WROW(5) + 256 + 4 * lane);
    float4 p6 = *reinterpret_cast<const float4*>(WROW(6) + 4 * lane);
    float4 q6 = *reinterpret_cast<const float4*>(WROW(6) + 256 + 4 * lane);
    float4 p7 = *reinterpret_cast<const float4*>(WROW(7) + 4 * lane);
    float4 q7 = *reinterpret_cast<const float4*>(WROW(7) + 256 + 4 * lane);
    #undef WROW
    PIN4(p0); PIN4(q0); PIN4(p1); PIN4(q1);
    PIN4(p2); PIN4(q2); PIN4(p3); PIN4(q3);
    PIN4(p4); PIN4(q4); PIN4(p5); PIN4(q5);
    PIN4(p6); PIN4(q6); PIN4(p7); PIN4(q7);

    unsigned long long* hb = hbuf + dir * 1024;      // [parity][512]
    const float* pred = pre + (size_t)dir * T_SEQ * G4;

    __shared__ float hsh[2][512];

    // publish own h0 slots (tag 0, parity 0)
    if (tid < JPB) {
        int j = b * JPB + tid;
        unsigned long long pv = (unsigned long long)__float_as_uint(h0[dir * H_DIM + j]);
        __hip_atomic_store(&hb[j], pv, __ATOMIC_RELAXED, __HIP_MEMORY_SCOPE_AGENT);
    }
    __syncthreads();

    const bool owner = (lane == 0) || (lane == 4);   // j = b*16+wv*2+(lane>>2)
    float c_reg = owner ? c0[dir * H_DIM + j_me] : 0.f;
    float pre_row = pred[row_me];                    // t=0 (8 lanes share addr -> bcast)

    for (int t = 0; t < T_SEQ; ++t) {
        const int par = t & 1;
        {
            unsigned long long v;
            do {
                v = __hip_atomic_load(&hb[par * 512 + tid], __ATOMIC_RELAXED, __HIP_MEMORY_SCOPE_AGENT);
            } while ((unsigned)(v >> 32) != (unsigned)t);
            hsh[par][tid] = __uint_as_float((unsigned)v);
        }
        __syncthreads();

        // matvec: 8 rows x 8 cols; h loads conflict-free b128
        const float* hv = hsh[par];
        float4 ha  = *reinterpret_cast<const float4*>(hv + 4 * lane);
        float4 hb4 = *reinterpret_cast<const float4*>(hv + 256 + 4 * lane);
        float acc0 = DOT8(ha, hb4, p0, q0);
        float acc1 = DOT8(ha, hb4, p1, q1);
        float acc2 = DOT8(ha, hb4, p2, q2);
        float acc3 = DOT8(ha, hb4, p3, q3);
        float acc4 = DOT8(ha, hb4, p4, q4);
        float acc5 = DOT8(ha, hb4, p5, q5);
        float acc6 = DOT8(ha, hb4, p6, q6);
        float acc7 = DOT8(ha, hb4, p7, q7);

        // butterfly 8->4->2->1 (rows keyed by lane bits), then oct reduce.
        // Lane L ends with row (L&7) total. All named scalars.
        const bool b1 = (lane & 1), b2 = (lane & 2), b4 = (lane & 4);
        float k0 = b1 ? acc1 : acc0, s0 = b1 ? acc0 : acc1;
        float k1 = b1 ? acc3 : acc2, s1 = b1 ? acc2 : acc3;
        float k2 = b1 ? acc5 : acc4, s2 = b1 ? acc4 : acc5;
        float k3 = b1 ? acc7 : acc6, s3 = b1 ? acc6 : acc7;
        float u0 = k0 + __shfl_xor(s0, 1);
        float u1 = k1 + __shfl_xor(s1, 1);
        float u2 = k2 + __shfl_xor(s2, 1);
        float u3 = k3 + __shfl_xor(s3, 1);
        float x0 = b2 ? u1 : u0, y0 = b2 ? u0 : u1;
        float x1 = b2 ? u3 : u2, y1 = b2 ? u2 : u3;
        float m0 = x0 + __shfl_xor(y0, 2);
        float m1 = x1 + __shfl_xor(y1, 2);
        float z0 = b4 ? m1 : m0, z1 = b4 ? m0 : m1;
        float vr = z0 + __shfl_xor(z1, 4);
        vr += __shfl_xor(vr, 8);
        vr += __shfl_xor(vr, 16);
        vr += __shfl_xor(vr, 32);

        float gv = vr + pre_row;                     // my home row's gate value

        if (t + 1 < T_SEQ)                           // prefetch next pre
            pre_row = pred[(size_t)(t + 1) * G4 + row_me];

        float act = (gme == 2) ? tanh_f(gv) : sigmoid_f(gv);

        // collect f,g,o onto gate-i lanes (r&3==0)
        float af = __shfl_xor(act, 1);
        float ag = __shfl_xor(act, 2);
        float ao = __shfl_xor(act, 3);

        if (owner) {                                 // lanes 0 and 4: rows r=0,4 (gate i)
            c_reg = af * c_reg + act * ag;
            float h = ao * tanh_f(c_reg);
            unsigned long long pv = ((unsigned long long)(unsigned)(t + 1) << 32)
                                  | (unsigned long long)__float_as_uint(h);
            __hip_atomic_store(&hb[((t + 1) & 1) * 512 + j_me], pv,
                               __ATOMIC_RELAXED, __HIP_MEMORY_SCOPE_AGENT);
            int ta = dir ? (T_SEQ - 1 - t) : t;
            hcat[(size_t)ta * 1024 + dir * H_DIM + j_me] = h;
        }
        // hsh parity double-buffered; next iteration's barrier orders
        // reads-before-overwrite (single barrier per step suffices).
    }
}

// ======================================================================
// K3: out[t][k] = hcat[t] . W_out[k] + b_out[k]
// ======================================================================
__global__ __launch_bounds__(256, 4)
void k_out(const float* __restrict__ hcat, const float* __restrict__ Wout,
           const float* __restrict__ bout, float* __restrict__ out)
{
    const int lane = threadIdx.x & 63;
    const int gw   = (blockIdx.x * 256 + threadIdx.x) >> 6;
    for (int t = gw; t < T_SEQ; t += 1024) {
        const float* hr = hcat + (size_t)t * 1024 + lane * 16;
        float4 h4[4];
        #pragma unroll
        for (int i = 0; i < 4; ++i) h4[i] = *reinterpret_cast<const float4*>(hr + 4 * i);
        float res = 0.f;
        for (int k = 0; k < 32; ++k) {
            const float* wr = Wout + (size_t)k * 1024 + lane * 16;
            float p = 0.f;
            #pragma unroll
            for (int i = 0; i < 4; ++i) {
                float4 w4 = *reinterpret_cast<const float4*>(wr + 4 * i);
                p = fmaf(h4[i].x, w4.x, p); p = fmaf(h4[i].y, w4.y, p);
                p = fmaf(h4[i].z, w4.z, p); p = fmaf(h4[i].w, w4.w, p);
            }
            p += __shfl_xor(p, 1);  p += __shfl_xor(p, 2);  p += __shfl_xor(p, 4);
            p += __shfl_xor(p, 8);  p += __shfl_xor(p, 16); p += __shfl_xor(p, 32);
            if (lane == k) res = p;
        }
        if (lane < 32) out[(size_t)t * 32 + lane] = res + bout[lane];
    }
}

// ======================================================================
extern "C" void kernel_launch(void* const* d_in, const int* in_sizes, int n_in,
                              void* d_out, int out_size, void* d_ws, size_t ws_size,
                              hipStream_t stream) {
    const int*   sent = (const int*)  d_in[0];
    const float* emb  = (const float*)d_in[1];
    const float* Wihf = (const float*)d_in[2];
    const float* Whhf = (const float*)d_in[3];
    const float* bihf = (const float*)d_in[4];
    const float* bhhf = (const float*)d_in[5];
    const float* Wihb = (const float*)d_in[6];
    const float* Whhb = (const float*)d_in[7];
    const float* bihb = (const float*)d_in[8];
    const float* bhhb = (const float*)d_in[9];
    const float* Wout = (const float*)d_in[10];
    const float* bout = (const float*)d_in[11];
    const float* h0   = (const float*)d_in[12];
    const float* c0   = (const float*)d_in[13];
    float* out = (float*)d_out;

    // workspace layout: pre (128 MB) | hcat (32 MB) | hbuf (16 KB)
    float* pre  = (float*)d_ws;
    float* hcat = pre + (size_t)2 * T_SEQ * G4;
    unsigned long long* hbuf = (unsigned long long*)(hcat + (size_t)T_SEQ * 1024);

    dim3 g1(G4 / 64, T_SEQ / 64, 2);
    k_pre<<<g1, 256, 0, stream>>>(sent, emb, Wihf, Wihb, bihf, bhhf, bihb, bhhb, pre);
    k_scan<<<64, 512, 0, stream>>>(pre, Whhf, Whhb, h0, c0, hcat, hbuf);
    k_out<<<256, 256, 0, stream>>>(hcat, Wout, bout, out);
}

// Round 7
// 11603.248 us; speedup vs baseline: 1.0889x; 1.0889x over previous
//
#include <hip/hip_runtime.h>
#include <hip/hip_bf16.h>

#define T_SEQ 8192
#define E_DIM 256
#define H_DIM 512
#define G4    2048   // 4*H
#define NBD   32     // blocks per direction
#define JPB   16     // h-elements per block

// ======================================================================
// K1: pre[dir][t][0:2048] = emb[sent(dir,t)] @ W_ih[dir]^T + (b_ih+b_hh)
// ======================================================================
__global__ __launch_bounds__(256, 4)
void k_pre(const int* __restrict__ sent, const float* __restrict__ emb,
           const float* __restrict__ Wf, const float* __restrict__ Wb,
           const float* __restrict__ bif, const float* __restrict__ bhf,
           const float* __restrict__ bib, const float* __restrict__ bhb,
           float* __restrict__ pre)
{
    const int jt  = blockIdx.x;
    const int tt  = blockIdx.y;
    const int dir = blockIdx.z;
    const float* W  = dir ? Wb : Wf;
    const float* bi = dir ? bib : bif;
    const float* bh = dir ? bhb : bhf;
    float* pred = pre + (size_t)dir * T_SEQ * G4;

    __shared__ float xs[64][65];
    __shared__ float ws[64][65];
    __shared__ int   ss[64];

    const int tid = threadIdx.x;
    if (tid < 64) {
        int trow = tt * 64 + tid;
        ss[tid] = sent[dir ? (T_SEQ - 1 - trow) : trow];
    }

    const int ty = tid >> 4, tx = tid & 15;
    const int lrow  = tid >> 2;
    const int cbase = (tid & 3) * 16;

    float acc[4][4] = {{0.f}};

    for (int kk0 = 0; kk0 < E_DIM; kk0 += 64) {
        __syncthreads();
        #pragma unroll
        for (int c = 0; c < 4; ++c) {
            int col = cbase + c * 4;
            float4 xv = *reinterpret_cast<const float4*>(emb + (size_t)ss[lrow] * E_DIM + kk0 + col);
            float4 wv = *reinterpret_cast<const float4*>(W + (size_t)(jt * 64 + lrow) * E_DIM + kk0 + col);
            xs[lrow][col+0] = xv.x; xs[lrow][col+1] = xv.y; xs[lrow][col+2] = xv.z; xs[lrow][col+3] = xv.w;
            ws[lrow][col+0] = wv.x; ws[lrow][col+1] = wv.y; ws[lrow][col+2] = wv.z; ws[lrow][col+3] = wv.w;
        }
        __syncthreads();
        #pragma unroll 8
        for (int k = 0; k < 64; ++k) {
            float a0 = xs[ty*4+0][k], a1 = xs[ty*4+1][k], a2 = xs[ty*4+2][k], a3 = xs[ty*4+3][k];
            float b0 = ws[tx*4+0][k], b1 = ws[tx*4+1][k], b2 = ws[tx*4+2][k], b3 = ws[tx*4+3][k];
            acc[0][0] = fmaf(a0,b0,acc[0][0]); acc[0][1] = fmaf(a0,b1,acc[0][1]);
            acc[0][2] = fmaf(a0,b2,acc[0][2]); acc[0][3] = fmaf(a0,b3,acc[0][3]);
            acc[1][0] = fmaf(a1,b0,acc[1][0]); acc[1][1] = fmaf(a1,b1,acc[1][1]);
            acc[1][2] = fmaf(a1,b2,acc[1][2]); acc[1][3] = fmaf(a1,b3,acc[1][3]);
            acc[2][0] = fmaf(a2,b0,acc[2][0]); acc[2][1] = fmaf(a2,b1,acc[2][1]);
            acc[2][2] = fmaf(a2,b2,acc[2][2]); acc[2][3] = fmaf(a2,b3,acc[2][3]);
            acc[3][0] = fmaf(a3,b0,acc[3][0]); acc[3][1] = fmaf(a3,b1,acc[3][1]);
            acc[3][2] = fmaf(a3,b2,acc[3][2]); acc[3][3] = fmaf(a3,b3,acc[3][3]);
        }
    }

    const int colg = jt * 64 + tx * 4;
    float bs[4];
    #pragma unroll
    for (int j = 0; j < 4; ++j) bs[j] = bi[colg + j] + bh[colg + j];
    #pragma unroll
    for (int i = 0; i < 4; ++i) {
        float4 r;
        r.x = acc[i][0] + bs[0]; r.y = acc[i][1] + bs[1];
        r.z = acc[i][2] + bs[2]; r.w = acc[i][3] + bs[3];
        *reinterpret_cast<float4*>(pred + (size_t)(tt*64 + ty*4 + i) * G4 + colg) = r;
    }
}

// ---------- fast activations (no NaN for large |x|) ----------
__device__ __forceinline__ float sigmoid_f(float x) {
    return 1.f / (1.f + __expf(-x));
}
__device__ __forceinline__ float tanh_f(float x) {
    float e = __expf(2.f * fabsf(x));            // inf ok: 2/(inf+1)=0
    float r = 1.f - 2.f / (e + 1.f);
    return copysignf(r, x);
}

typedef _Float16 half2_t __attribute__((ext_vector_type(2)));

__device__ __forceinline__ unsigned pack_h2(float lo, float hi) {
    half2_t p;
    p.x = (_Float16)lo; p.y = (_Float16)hi;
    return __builtin_bit_cast(unsigned, p);
}

__device__ __forceinline__ float dot2_acc(unsigned w, unsigned h, float acc) {
#if __has_builtin(__builtin_amdgcn_fdot2)
    return __builtin_amdgcn_fdot2(__builtin_bit_cast(half2_t, w),
                                  __builtin_bit_cast(half2_t, h), acc, false);
#else
    half2_t wp = __builtin_bit_cast(half2_t, w);
    half2_t hp = __builtin_bit_cast(half2_t, h);
    acc = fmaf((float)wp.x, (float)hp.x, acc);
    acc = fmaf((float)wp.y, (float)hp.y, acc);
    return acc;
#endif
}

__device__ __forceinline__ float dot8_f16(uint4 w, uint4 h) {
    float a = dot2_acc(w.x, h.x, 0.f);
    a = dot2_acc(w.y, h.y, a);
    a = dot2_acc(w.z, h.z, a);
    a = dot2_acc(w.w, h.w, a);
    return a;
}

// ======================================================================
// K2: two LSTM scans. 64 persistent blocks (32/dir) x 512 threads.
// Block owns 16 h (64 gate-rows). Weights live in LDS as fp16 (64 KB):
// allocator-proof after 3 rounds of the register allocator spilling any
// >8-value per-thread weight set to scratch (VGPR stuck at 52).
// Per step: 8 ds_read_b128 weight reads issued via inline asm BEFORE the
// poll spin -> they drain on the LDS pipe while the wave spins on VMEM;
// the pre-barrier lgkmcnt(0) guarantees completion before first use.
// Matvec = v_dot2_f32_f16 (fp32 accumulate). h staged in LDS as fp16.
// h exchange: step-tagged 64-bit agent-scope atomics, parity dbuf.
// ======================================================================
__global__ __launch_bounds__(512, 1)
void k_scan(const float* __restrict__ pre,
            const float* __restrict__ Whhf, const float* __restrict__ Whhb,
            const float* __restrict__ h0, const float* __restrict__ c0,
            float* __restrict__ hcat, unsigned long long* __restrict__ hbuf)
{
    const int bid  = blockIdx.x;
    const int dir  = (bid >> 2) & 1;               // dir0 -> XCD 0-3, dir1 -> 4-7
    const int b    = (bid >> 3) * 4 + (bid & 3);   // 0..31 within dir
    const int tid  = threadIdx.x;
    const int wv   = tid >> 6;          // 0..7
    const int lane = tid & 63;
    const int r    = lane & 7;          // home row after butterfly
    const int gme  = r & 3;             // gate of home row (i,f,g,o)
    const int j_me = b * JPB + wv * 2 + (r >> 2);
    const int row_me = gme * H_DIM + j_me;

    const float* Whh = dir ? Whhb : Whhf;
    const int jbase = b * JPB + wv * 2;

    __shared__ uint4    wlds[8][8][64];   // [wave][row][lane] fp16x8 = 64 KB
    __shared__ _Float16 hsh16[2][512];    // staged h, fp16

    // stage this thread's 8 rows x 8 cols (contiguous cols 8*lane..+7)
    for (int r2 = 0; r2 < 8; ++r2) {
        int rr = (r2 & 3) * H_DIM + jbase + (r2 >> 2);
        const float* wr = Whh + (size_t)rr * H_DIM + 8 * lane;
        float4 a  = *reinterpret_cast<const float4*>(wr);
        float4 c4 = *reinterpret_cast<const float4*>(wr + 4);
        uint4 u;
        u.x = pack_h2(a.x,  a.y);  u.y = pack_h2(a.z,  a.w);
        u.z = pack_h2(c4.x, c4.y); u.w = pack_h2(c4.z, c4.w);
        wlds[wv][r2][lane] = u;
    }

    unsigned long long* hb = hbuf + dir * 1024;      // [parity][512]
    const float* pred = pre + (size_t)dir * T_SEQ * G4;

    // publish own h0 slots (tag 0, parity 0)
    if (tid < JPB) {
        int j = b * JPB + tid;
        unsigned long long pv = (unsigned long long)__float_as_uint(h0[dir * H_DIM + j]);
        __hip_atomic_store(&hb[j], pv, __ATOMIC_RELAXED, __HIP_MEMORY_SCOPE_AGENT);
    }
    __syncthreads();                                 // weights staged, h0 out

    const bool owner = (lane == 0) || (lane == 4);
    float c_reg = owner ? c0[dir * H_DIM + j_me] : 0.f;
    float pre_row = pred[row_me];                    // t=0 prefetch

    // LDS byte address of this thread's weight row 0 (rows stride 1024 B)
    const unsigned wbase = (unsigned)(size_t)&wlds[wv][0][lane];

    for (int t = 0; t < T_SEQ; ++t) {
        const int par = t & 1;

        // issue weight reads first: LDS pipe works while we spin on VMEM
        uint4 u0,u1,u2,u3,u4,u5,u6,u7;
        asm volatile("ds_read_b128 %0, %8 offset:0\n\t"
                     "ds_read_b128 %1, %8 offset:1024\n\t"
                     "ds_read_b128 %2, %8 offset:2048\n\t"
                     "ds_read_b128 %3, %8 offset:3072\n\t"
                     "ds_read_b128 %4, %8 offset:4096\n\t"
                     "ds_read_b128 %5, %8 offset:5120\n\t"
                     "ds_read_b128 %6, %8 offset:6144\n\t"
                     "ds_read_b128 %7, %8 offset:7168"
                     : "=v"(u0),"=v"(u1),"=v"(u2),"=v"(u3),
                       "=v"(u4),"=v"(u5),"=v"(u6),"=v"(u7)
                     : "v"(wbase));

        unsigned long long v;
        do {
            v = __hip_atomic_load(&hb[par * 512 + tid], __ATOMIC_RELAXED, __HIP_MEMORY_SCOPE_AGENT);
        } while ((unsigned)(v >> 32) != (unsigned)t);
        hsh16[par][tid] = (_Float16)__uint_as_float((unsigned)v);
        __syncthreads();   // lgkmcnt(0) before barrier drains asm reads too

        uint4 hu = reinterpret_cast<const uint4*>(&hsh16[par][0])[lane];
        float acc0 = dot8_f16(u0, hu);
        float acc1 = dot8_f16(u1, hu);
        float acc2 = dot8_f16(u2, hu);
        float acc3 = dot8_f16(u3, hu);
        float acc4 = dot8_f16(u4, hu);
        float acc5 = dot8_f16(u5, hu);
        float acc6 = dot8_f16(u6, hu);
        float acc7 = dot8_f16(u7, hu);

        // butterfly 8->4->2->1 (rows keyed by lane bits), then oct reduce.
        const bool b1 = (lane & 1), b2 = (lane & 2), b4 = (lane & 4);
        float k0 = b1 ? acc1 : acc0, s0 = b1 ? acc0 : acc1;
        float k1 = b1 ? acc3 : acc2, s1 = b1 ? acc2 : acc3;
        float k2 = b1 ? acc5 : acc4, s2 = b1 ? acc4 : acc5;
        float k3 = b1 ? acc7 : acc6, s3 = b1 ? acc6 : acc7;
        float uu0 = k0 + __shfl_xor(s0, 1);
        float uu1 = k1 + __shfl_xor(s1, 1);
        float uu2 = k2 + __shfl_xor(s2, 1);
        float uu3 = k3 + __shfl_xor(s3, 1);
        float x0 = b2 ? uu1 : uu0, y0 = b2 ? uu0 : uu1;
        float x1 = b2 ? uu3 : uu2, y1 = b2 ? uu2 : uu3;
        float m0 = x0 + __shfl_xor(y0, 2);
        float m1 = x1 + __shfl_xor(y1, 2);
        float z0 = b4 ? m1 : m0, z1 = b4 ? m0 : m1;
        float vr = z0 + __shfl_xor(z1, 4);
        vr += __shfl_xor(vr, 8);
        vr += __shfl_xor(vr, 16);
        vr += __shfl_xor(vr, 32);

        float gv = vr + pre_row;                     // home row's gate value

        if (t + 1 < T_SEQ)                           // prefetch next pre
            pre_row = pred[(size_t)(t + 1) * G4 + row_me];

        float act = (gme == 2) ? tanh_f(gv) : sigmoid_f(gv);

        float af = __shfl_xor(act, 1);
        float ag = __shfl_xor(act, 2);
        float ao = __shfl_xor(act, 3);

        if (owner) {                                 // lanes 0/4: gate-i rows
            c_reg = af * c_reg + act * ag;
            float h = ao * tanh_f(c_reg);
            unsigned long long pv = ((unsigned long long)(unsigned)(t + 1) << 32)
                                  | (unsigned long long)__float_as_uint(h);
            __hip_atomic_store(&hb[((t + 1) & 1) * 512 + j_me], pv,
                               __ATOMIC_RELAXED, __HIP_MEMORY_SCOPE_AGENT);
            int ta = dir ? (T_SEQ - 1 - t) : t;
            hcat[(size_t)ta * 1024 + dir * H_DIM + j_me] = h;
        }
        // hsh16 parity double-buffered; next iteration's barrier orders
        // reads-before-overwrite (single barrier per step suffices).
    }
}

// ======================================================================
// K3: out[t][k] = hcat[t] . W_out[k] + b_out[k]
// ======================================================================
__global__ __launch_bounds__(256, 4)
void k_out(const float* __restrict__ hcat, const float* __restrict__ Wout,
           const float* __restrict__ bout, float* __restrict__ out)
{
    const int lane = threadIdx.x & 63;
    const int gw   = (blockIdx.x * 256 + threadIdx.x) >> 6;
    for (int t = gw; t < T_SEQ; t += 1024) {
        const float* hr = hcat + (size_t)t * 1024 + lane * 16;
        float4 h4[4];
        #pragma unroll
        for (int i = 0; i < 4; ++i) h4[i] = *reinterpret_cast<const float4*>(hr + 4 * i);
        float res = 0.f;
        for (int k = 0; k < 32; ++k) {
            const float* wr = Wout + (size_t)k * 1024 + lane * 16;
            float p = 0.f;
            #pragma unroll
            for (int i = 0; i < 4; ++i) {
                float4 w4 = *reinterpret_cast<const float4*>(wr + 4 * i);
                p = fmaf(h4[i].x, w4.x, p); p = fmaf(h4[i].y, w4.y, p);
                p = fmaf(h4[i].z, w4.z, p); p = fmaf(h4[i].w, w4.w, p);
            }
            p += __shfl_xor(p, 1);  p += __shfl_xor(p, 2);  p += __shfl_xor(p, 4);
            p += __shfl_xor(p, 8);  p += __shfl_xor(p, 16); p += __shfl_xor(p, 32);
            if (lane == k) res = p;
        }
        if (lane < 32) out[(size_t)t * 32 + lane] = res + bout[lane];
    }
}

// ======================================================================
extern "C" void kernel_launch(void* const* d_in, const int* in_sizes, int n_in,
                              void* d_out, int out_size, void* d_ws, size_t ws_size,
                              hipStream_t stream) {
    const int*   sent = (const int*)  d_in[0];
    const float* emb  = (const float*)d_in[1];
    const float* Wihf = (const float*)d_in[2];
    const float* Whhf = (const float*)d_in[3];
    const float* bihf = (const float*)d_in[4];
    const float* bhhf = (const float*)d_in[5];
    const float* Wihb = (const float*)d_in[6];
    const float* Whhb = (const float*)d_in[7];
    const float* bihb = (const float*)d_in[8];
    const float* bhhb = (const float*)d_in[9];
    const float* Wout = (const float*)d_in[10];
    const float* bout = (const float*)d_in[11];
    const float* h0   = (const float*)d_in[12];
    const float* c0   = (const float*)d_in[13];
    float* out = (float*)d_out;

    // workspace layout: pre (128 MB) | hcat (32 MB) | hbuf (16 KB)
    float* pre  = (float*)d_ws;
    float* hcat = pre + (size_t)2 * T_SEQ * G4;
    unsigned long long* hbuf = (unsigned long long*)(hcat + (size_t)T_SEQ * 1024);

    dim3 g1(G4 / 64, T_SEQ / 64, 2);
    k_pre<<<g1, 256, 0, stream>>>(sent, emb, Wihf, Wihb, bihf, bhhf, bihb, bhhb, pre);
    k_scan<<<64, 512, 0, stream>>>(pre, Whhf, Whhb, h0, c0, hcat, hbuf);
    k_out<<<256, 256, 0, stream>>>(hcat, Wout, bout, out);
}